// Round 8
// baseline (159.708 us; speedup 1.0000x reference)
//
#include <hip/hip_runtime.h>

// ECE: ece = sum_b | S_b | / n,  S_b = sum_{i in b} conf_i - count_{i in b}(acc_i=1)
// Bin: tf = ceilf(c*15) compared as FLOAT against b+1 (b in 0..14). Validity
// free: c<=0 -> tf<=0, c>1 -> tf>15, NaN -> compares false. acc in {0,1} exact.
//
// Ladder: R1 LDS atomics serialize. R2 LDS RMW chains 47us. R3 reg-bins 48us.
// R4 lost occupancy 68us. R5 grid.sync +100us. R6 contiguous 56us. R7
// global_load_lds pipeline 50us. Four structures pinned at ~48us, all moving
// 134MB at ~2.8 TB/s (FETCH=65.6MB: half L3, half HBM). m13 read-half ~3.15
// TB/s suggests a ~3.2 TB/s read-fabric ceiling -> floor ~42us.
// R8 decisive experiment: halve VALU/elem. (1) acc-side via ballot+popcount:
// s_and/s_bcnt1/s_add on the idle SALU pipe (matches reference algebra
// sum_conf - sum_acc). (2) float-compare binning (no cvt). 49 VALU/elem vs
// ~85. If dur unchanged at VALUBusy ~24% -> read-pattern ceiling confirmed.

#define NB 15

__device__ __forceinline__ void slot(float v, float a,
                                     float* __restrict__ bins,
                                     int* __restrict__ cnt) {
    float tf = ceilf(v * 15.0f);                  // valid => 1.0..15.0
    unsigned long long am = __ballot(a == 1.0f);  // wave-uniform (SGPR pair)
#pragma unroll
    for (int b = 0; b < NB; ++b) {
        bool m = (tf == (float)(b + 1));
        unsigned long long mb = __ballot(m);      // same v_cmp feeds cndmask
        bins[b] += m ? v : 0.0f;                  // float: conf side only
        cnt[b] += __popcll(mb & am);              // SALU: acc side
    }
}

__device__ __forceinline__ void proc4(float4 c, float4 a,
                                      float* __restrict__ bins,
                                      int* __restrict__ cnt) {
    slot(c.x, a.x, bins, cnt);
    slot(c.y, a.y, bins, cnt);
    slot(c.z, a.z, bins, cnt);
    slot(c.w, a.w, bins, cnt);
}

__global__ __launch_bounds__(256, 8) void ece_hist(
        const float* __restrict__ conf,
        const float* __restrict__ acc,
        float* __restrict__ partials,   // layout [NB][nblocks]
        int n4, int n, int nblocks) {
    float bins[NB];
    int cnt[NB];
#pragma unroll
    for (int b = 0; b < NB; ++b) { bins[b] = 0.0f; cnt[b] = 0; }

    const float4* __restrict__ c4 = (const float4*)conf;
    const float4* __restrict__ a4 = (const float4*)acc;
    const int stride = gridDim.x * blockDim.x;
    int i = blockIdx.x * blockDim.x + threadIdx.x;

    // 4-wide: 8 dwordx4 loads issued before compute
    for (; i + 3 * stride < n4; i += 4 * stride) {
        float4 c0 = c4[i];
        float4 a0 = a4[i];
        float4 c1 = c4[i + stride];
        float4 a1 = a4[i + stride];
        float4 c2 = c4[i + 2 * stride];
        float4 a2 = a4[i + 2 * stride];
        float4 c3 = c4[i + 3 * stride];
        float4 a3 = a4[i + 3 * stride];
        proc4(c0, a0, bins, cnt);
        proc4(c1, a1, bins, cnt);
        proc4(c2, a2, bins, cnt);
        proc4(c3, a3, bins, cnt);
    }
    for (; i < n4; i += stride) proc4(c4[i], a4[i], bins, cnt);

    // scalar tail (n % 4) — block 0 only; ballot is exec-mask-correct
    if (blockIdx.x == 0) {
        for (int k = n4 * 4 + (int)threadIdx.x; k < n; k += blockDim.x)
            slot(conf[k], acc[k], bins, cnt);
    }

    // wave reduction of the float (conf) side; cnt is already wave-total
#pragma unroll
    for (int b = 0; b < NB; ++b) {
        float v = bins[b];
#pragma unroll
        for (int off = 32; off > 0; off >>= 1)
            v += __shfl_down(v, off, 64);
        bins[b] = v;
    }

    __shared__ float wsum[4][NB];       // 256 threads = 4 waves
    const int wave = threadIdx.x >> 6;
    const int lane = threadIdx.x & 63;
    if (lane == 0) {
#pragma unroll
        for (int b = 0; b < NB; ++b)
            wsum[wave][b] = bins[b] - (float)cnt[b];   // S_b per wave
    }
    __syncthreads();

    if (threadIdx.x < NB) {
        float s = wsum[0][threadIdx.x] + wsum[1][threadIdx.x]
                + wsum[2][threadIdx.x] + wsum[3][threadIdx.x];
        partials[threadIdx.x * nblocks + blockIdx.x] = s;   // no atomics
    }
}

__global__ __launch_bounds__(960) void ece_final(
        const float* __restrict__ partials,  // [NB][nblocks]
        float* __restrict__ out, int nblocks, float inv_n) {
    __shared__ float bsum[NB];
    const int wave = threadIdx.x >> 6;   // 15 waves, one per bin
    const int lane = threadIdx.x & 63;

    float s = 0.0f;
    for (int i = lane; i < nblocks; i += 64)
        s += partials[wave * nblocks + i];   // coalesced per wave
#pragma unroll
    for (int off = 32; off > 0; off >>= 1)
        s += __shfl_down(s, off, 64);
    if (lane == 0) bsum[wave] = s;
    __syncthreads();

    if (threadIdx.x == 0) {
        float t = 0.0f;
#pragma unroll
        for (int b = 0; b < NB; ++b) t += fabsf(bsum[b]);
        out[0] = t * inv_n;
    }
}

extern "C" void kernel_launch(void* const* d_in, const int* in_sizes, int n_in,
                              void* d_out, int out_size, void* d_ws, size_t ws_size,
                              hipStream_t stream) {
    const float* conf = (const float*)d_in[0];
    const float* acc  = (const float*)d_in[1];
    float* partials   = (float*)d_ws;
    float* out        = (float*)d_out;

    const int n  = in_sizes[0];
    const int n4 = n / 4;

    int nblocks = 2048;                          // 8 blocks/CU
    while ((size_t)NB * nblocks * sizeof(float) > ws_size && nblocks > 1)
        nblocks >>= 1;
    int max_grid = (n4 + 255) / 256;
    if (nblocks > max_grid) nblocks = max_grid;
    if (nblocks < 1) nblocks = 1;

    ece_hist<<<nblocks, 256, 0, stream>>>(conf, acc, partials, n4, n, nblocks);
    ece_final<<<1, 960, 0, stream>>>(partials, out, nblocks, 1.0f / (float)n);
}

// Round 10
// 156.847 us; speedup vs baseline: 1.0182x; 1.0182x over previous
//
#include <hip/hip_runtime.h>

// ECE: ece = sum_b | sum_{i in b} (conf_i - acc_i) | / n
// Bin: tt = ceil(c*15), bin b matches tt == b+1. Validity free: c<=0 -> tt<=0,
// c>1 -> tt>15, NaN -> 0 -- none match any bin.
//
// Ladder: R1 LDS atomics serialize (~210cyc). R2 LDS RMW chain 47us. R3
// reg-bins 48us. R4 occupancy loss 68us. R5 grid.sync +100us. R6 contiguous
// 56us. R7 global_load_lds pinned pipeline 50us. R8 ballot 50us. R9 asm
// reg-pipeline: UNSOUND (compiler copies asm-load dest regs before the
// cross-statement waitcnt -> NaN). Five passing structures all ~2.8 TB/s
// combined read == m13's copy read-half (3.15 TB/s) => XCD-fabric read-path
// ceiling ~3.2 TB/s chip-wide; L3 hits don't help (far side of the link);
// floor = 134 MB / 3.15 TB/s ~= 42.6us; we sit at ~90%.
// R10: revert to best passing structure (R3) + last untested theory:
// paired-stream channel congruence. conf is software-pipelined TWO
// grid-strides ahead in registers, so simultaneously-issued conf/acc
// addresses differ by ~16 MB (decorrelated channels) while pairing is
// preserved. Null result => fabric roofline confirmed, declare next round.

#define NB 15

__device__ __forceinline__ void proc4(float4 c, float4 a, float* __restrict__ bins) {
    float cv[4] = {c.x, c.y, c.z, c.w};
    float av[4] = {a.x, a.y, a.z, a.w};
#pragma unroll
    for (int j = 0; j < 4; ++j) {
        float v = cv[j];
        float d = v - av[j];
        int tt = (int)ceilf(v * 15.0f);   // valid => tt in 1..15
#pragma unroll
        for (int b = 0; b < NB; ++b)
            bins[b] += (tt == b + 1) ? d : 0.0f;   // b+1 inline const
    }
}

__global__ __launch_bounds__(256, 8) void ece_hist(
        const float* __restrict__ conf,
        const float* __restrict__ acc,
        float* __restrict__ partials,   // layout [NB][nblocks]
        int n4, int n, int nblocks) {
    float bins[NB];
#pragma unroll
    for (int b = 0; b < NB; ++b) bins[b] = 0.0f;

    const float4* __restrict__ c4 = (const float4*)conf;
    const float4* __restrict__ a4 = (const float4*)acc;
    const int stride = gridDim.x * blockDim.x;
    int i = blockIdx.x * blockDim.x + threadIdx.x;

    // conf pipelined 2 grid-strides ahead of acc: simultaneous loads are
    // ~16 MB apart -> no channel congruence between the two streams.
    if (i + stride < n4) {
        float4 c0 = c4[i];
        float4 c1 = c4[i + stride];
        for (; i + 3 * stride < n4; i += 2 * stride) {
            float4 c2 = c4[i + 2 * stride];   // conf, 2 ahead
            float4 c3 = c4[i + 3 * stride];
            float4 a0 = a4[i];                // acc, current
            float4 a1 = a4[i + stride];
            proc4(c0, a0, bins);
            proc4(c1, a1, bins);
            c0 = c2;
            c1 = c3;
        }
        // pairs for current i (and i+stride) still pending: finish below
    }
    for (; i < n4; i += stride) proc4(c4[i], a4[i], bins);

    // scalar tail (n % 4) — block 0 only
    if (blockIdx.x == 0) {
        for (int k = n4 * 4 + (int)threadIdx.x; k < n; k += blockDim.x) {
            float v = conf[k];
            float d = v - acc[k];
            int tt = (int)ceilf(v * 15.0f);
#pragma unroll
            for (int b = 0; b < NB; ++b)
                bins[b] += (tt == b + 1) ? d : 0.0f;
        }
    }

    // wave reduction (64 lanes)
#pragma unroll
    for (int b = 0; b < NB; ++b) {
        float v = bins[b];
#pragma unroll
        for (int off = 32; off > 0; off >>= 1)
            v += __shfl_down(v, off, 64);
        bins[b] = v;
    }

    __shared__ float wsum[4][NB];       // 256 threads = 4 waves
    const int wave = threadIdx.x >> 6;
    const int lane = threadIdx.x & 63;
    if (lane == 0) {
#pragma unroll
        for (int b = 0; b < NB; ++b) wsum[wave][b] = bins[b];
    }
    __syncthreads();

    if (threadIdx.x < NB) {
        float s = wsum[0][threadIdx.x] + wsum[1][threadIdx.x]
                + wsum[2][threadIdx.x] + wsum[3][threadIdx.x];
        partials[threadIdx.x * nblocks + blockIdx.x] = s;   // no atomics
    }
}

__global__ __launch_bounds__(960) void ece_final(
        const float* __restrict__ partials,  // [NB][nblocks]
        float* __restrict__ out, int nblocks, float inv_n) {
    __shared__ float bsum[NB];
    const int wave = threadIdx.x >> 6;   // 15 waves, one per bin
    const int lane = threadIdx.x & 63;

    float s = 0.0f;
    for (int i = lane; i < nblocks; i += 64)
        s += partials[wave * nblocks + i];   // coalesced per wave
#pragma unroll
    for (int off = 32; off > 0; off >>= 1)
        s += __shfl_down(s, off, 64);
    if (lane == 0) bsum[wave] = s;
    __syncthreads();

    if (threadIdx.x == 0) {
        float t = 0.0f;
#pragma unroll
        for (int b = 0; b < NB; ++b) t += fabsf(bsum[b]);
        out[0] = t * inv_n;
    }
}

extern "C" void kernel_launch(void* const* d_in, const int* in_sizes, int n_in,
                              void* d_out, int out_size, void* d_ws, size_t ws_size,
                              hipStream_t stream) {
    const float* conf = (const float*)d_in[0];
    const float* acc  = (const float*)d_in[1];
    float* partials   = (float*)d_ws;
    float* out        = (float*)d_out;

    const int n  = in_sizes[0];
    const int n4 = n / 4;

    int nblocks = 2048;                          // 8 blocks/CU
    while ((size_t)NB * nblocks * sizeof(float) > ws_size && nblocks > 1)
        nblocks >>= 1;
    int max_grid = (n4 + 255) / 256;
    if (nblocks > max_grid) nblocks = max_grid;
    if (nblocks < 1) nblocks = 1;

    ece_hist<<<nblocks, 256, 0, stream>>>(conf, acc, partials, n4, n, nblocks);
    ece_final<<<1, 960, 0, stream>>>(partials, out, nblocks, 1.0f / (float)n);
}